// Round 12
// baseline (146.393 us; speedup 1.0000x reference)
//
#include <hip/hip_runtime.h>

// BackgroundNoiseLayer, round 12: page-sized output streaming.
//   out[t, n*5+r] = sum_k spikes[t,k] * W[k, n*5+r],
//   W[k, c] = scatter-add over edges e (cols[e]=k, rows[e]=n) of weights[e]*tau[e,r]
//
// Theory under test: the ~3x write-BW shortfall of all prior rounds is DRAM
// page thrashing from 320B-per-1MB-stride output segments. K2b writes 4KB
// per row per block, address-sequential in time -> full-page writes.
//
// memset: zero counters [part][bin]
// K1 : bucket edges (bin=row/16, 16B records, XCD-partitioned) + spike table.
// K2a: per bin: preload records -> zero f32 LDS slice -> LDS atomic scatter ->
//      convert, writing bf16 MFMA fragments DIRECTLY to global Wg
//      [mtile][kk][lane] (no LDS bf16 area, no swizzle).
// K2b: pure streaming GEMM: block = 64 t x 1008 c; per m-tile: 4 Wg loads
//      (L2/L3-hot) -> 4 MFMA -> f32x4 store. No LDS, no barriers.

#define N_NEURONS 50000
#define N_BKG     100
#define N_SYN     5
#define N_EDGES   500000
#define SEQ_T     250
#define NCOL      (N_NEURONS * N_SYN)   // 250000
#define RPB       16                    // neurons per bin
#define NBINS     (N_NEURONS / RPB)     // 3125
#define NPART     8                     // record partitions (one per XCD)
#define CAP_P     64                    // records per (bin, part)
#define RECS_BIN  (NPART * CAP_P)       // 512 records / bin
#define CPADF     80                    // f32 slice leading dim
#define NMT       15625                 // total m-tiles (c/16)
#define MT_BLK    63                    // m-tiles per K2b block (248*63+1=15625)

#define LDS_BYTES 32000                 // f32 slice 100*80*4

// d_ws layout
#define WS_COUNT_OFF 0                  // NPART*NBINS u32 = 100 KB
#define WS_SPB_OFF   131072             // 4096 * 16 B = 64 KB spike frags
#define WS_REC_OFF   262144             // NBINS*512*16 B = 25.6 MB
#define WS_WG_OFF    25862144           // NMT*4*64*16 B = 64 MB

typedef __attribute__((ext_vector_type(8))) short bf16x8;
typedef __attribute__((ext_vector_type(4))) float f32x4;

__device__ inline unsigned short bf16_rne(float f) {
    unsigned u = __builtin_bit_cast(unsigned, f);
    u += 0x7FFFu + ((u >> 16) & 1u);
    return (unsigned short)(u >> 16);
}
__device__ inline float bf16_up(unsigned hw) {
    return __builtin_bit_cast(float, hw << 16);
}

// K1: bucket-append edges into XCD-local partition; gids < 4096 also build
// the fragment-ordered spike table: unit gid = (nt*4 + kk)*64 + lane,
// value[i] = bf16(spikes[t, k0+i]), t = nt*16+(lane&15), k0 = kk*32+(lane>>4)*8.
__global__ __launch_bounds__(256) void bucket_kernel(
        const float* __restrict__ weights,
        const float* __restrict__ tau,
        const int*   __restrict__ rows,
        const int*   __restrict__ cols,
        const float* __restrict__ spikes,
        unsigned* __restrict__ count,
        uint4* __restrict__ rec,
        bf16x8* __restrict__ spbf) {
    int gid = blockIdx.x * 256 + threadIdx.x;
    if (gid < 4096) {
        int lane = gid & 63;
        int kk   = (gid >> 6) & 3;
        int nt   = gid >> 8;
        int t    = nt * 16 + (lane & 15);
        int k0   = kk * 32 + (lane >> 4) * 8;
        bf16x8 v;
#pragma unroll
        for (int i = 0; i < 8; ++i) {
            float s = 0.f;
            if (t < SEQ_T && (k0 + i) < N_BKG)
                s = spikes[t * N_BKG + k0 + i];      // 0/1 -> bf16 exact
            v[i] = (short)bf16_rne(s);
        }
        spbf[gid] = v;
    }
    if (gid >= N_EDGES) return;
    int row = rows[gid];
    int col = cols[gid];
    float w = weights[gid];
    const float* tp = tau + (size_t)gid * N_SYN;
    int bin  = row >> 4;
    int part = blockIdx.x & (NPART - 1);         // XCD-local partition
    unsigned slot = atomicAdd(&count[part * NBINS + bin], 1u);
    if (slot >= CAP_P) return;                   // statistically impossible
    uint4 r;
    r.x = ((unsigned)col << 4) | (unsigned)(row & 15);
    r.y = (unsigned)bf16_rne(w * tp[0]) | ((unsigned)bf16_rne(w * tp[1]) << 16);
    r.z = (unsigned)bf16_rne(w * tp[2]) | ((unsigned)bf16_rne(w * tp[3]) << 16);
    r.w = (unsigned)bf16_rne(w * tp[4]);
    rec[(size_t)bin * RECS_BIN + part * CAP_P + slot] = r;
}

// K2a: scatter + convert -> Wg fragments. 3125 blocks x 256 (4 waves).
// Wg[mtile][kk][lane][i] = W[kk*32+(lane>>4)*8+i][mtile*16+(lane&15)], bf16.
__global__ __launch_bounds__(256, 4) void scatter_kernel(
        const unsigned* __restrict__ count,
        const uint4* __restrict__ rec,
        bf16x8* __restrict__ wg) {
    __shared__ __align__(16) float slice[N_BKG * CPADF];   // [100][80] f32

    const int tid = threadIdx.x;
    const int bin = blockIdx.x;
    const int l   = tid & 63;
    const int wv  = tid >> 6;

    // ---- preload records: wave wv owns partitions wv and wv+4 ----
    const uint4* rbin = rec + (size_t)bin * RECS_BIN;
    unsigned cntA = count[wv * NBINS + bin];
    unsigned cntB = count[(4 + wv) * NBINS + bin];
    if (cntA > CAP_P) cntA = CAP_P;
    if (cntB > CAP_P) cntB = CAP_P;
    uint4 ra = rbin[wv * CAP_P + l];             // unguarded: region allocated
    uint4 rb = rbin[(4 + wv) * CAP_P + l];
    bool havea = (unsigned)l < cntA;
    bool haveb = (unsigned)l < cntB;

    // ---- zero f32 slice (8000 f32 = 2000 f32x4) ----
    {
        f32x4* s4 = (f32x4*)slice;
        f32x4 z = (f32x4){0.f, 0.f, 0.f, 0.f};
#pragma unroll
        for (int j = 0; j < 8; ++j) {
            int i = tid + j * 256;
            if (i < 2000) s4[i] = z;
        }
    }
    __syncthreads();

    // ---- LDS f32 atomic scatter ----
    if (havea) {
        float* bp = &slice[(ra.x >> 4) * CPADF + (ra.x & 15u) * N_SYN];
        atomicAdd(bp + 0, bf16_up(ra.y & 0xFFFFu));
        atomicAdd(bp + 1, bf16_up(ra.y >> 16));
        atomicAdd(bp + 2, bf16_up(ra.z & 0xFFFFu));
        atomicAdd(bp + 3, bf16_up(ra.z >> 16));
        atomicAdd(bp + 4, bf16_up(ra.w & 0xFFFFu));
    }
    if (haveb) {
        float* bp = &slice[(rb.x >> 4) * CPADF + (rb.x & 15u) * N_SYN];
        atomicAdd(bp + 0, bf16_up(rb.y & 0xFFFFu));
        atomicAdd(bp + 1, bf16_up(rb.y >> 16));
        atomicAdd(bp + 2, bf16_up(rb.z & 0xFFFFu));
        atomicAdd(bp + 3, bf16_up(rb.z >> 16));
        atomicAdd(bp + 4, bf16_up(rb.w & 0xFFFFu));
    }
    __syncthreads();

    // ---- convert: read slice, write bf16 fragments straight to Wg ----
    // 1280 units: c = u%80 (col in bin), kb = u/80 (8-k group 0..15).
    // lane = (c&15) | ((kb&3)<<4), kk = kb>>2, mtile = bin*5 + c/16.
#pragma unroll
    for (int j = 0; j < 5; ++j) {
        int u  = tid + j * 256;                  // 0..1279
        int c  = u % 80;
        int kb = u / 80;
        bf16x8 v;
#pragma unroll
        for (int i = 0; i < 8; ++i) {
            int k = kb * 8 + i;
            float f = (k < N_BKG) ? slice[k * CPADF + c] : 0.f;
            v[i] = (short)bf16_rne(f);
        }
        size_t idx = ((size_t)(bin * 5 + (c >> 4)) * 4 + (kb >> 2)) * 64
                   + ((c & 15) | ((kb & 3) << 4));
        wg[idx] = v;
    }
}

// K2b: pure streaming MFMA GEMM. grid (249, 4), 256 thr (4 waves), no LDS.
// Block: t-group blockIdx.y (64 rows; wave wv = n-tile), c-range blockIdx.x
// (63 m-tiles; block 248 has 1). Per m: 4 Wg frag loads -> 4 MFMA -> f32x4
// store. Row writes are address-sequential across the m-sweep (4KB/row/block).
// D: col = t = l&15, row = c = (l>>4)*4+reg (mapping verified rounds 5-11).
__global__ __launch_bounds__(256, 4) void gemm_kernel(
        const bf16x8* __restrict__ wg,
        const bf16x8* __restrict__ spbf,
        float* __restrict__ out) {
    const int tid = threadIdx.x;
    const int l   = tid & 63;
    const int wv  = tid >> 6;
    const int lc  = l & 15;
    const int lq  = l >> 4;
    const int cr  = blockIdx.x;                  // c-range
    const int nt  = blockIdx.y * 4 + wv;         // n-tile 0..15
    const int t   = nt * 16 + lc;                // 0..255
    const int m0  = cr * MT_BLK;
    const int mcnt = (cr < 248) ? MT_BLK : (NMT - 248 * MT_BLK);   // 63 or 1

    bf16x8 bs[4];
#pragma unroll
    for (int kk = 0; kk < 4; ++kk)
        bs[kk] = spbf[(nt * 4 + kk) * 64 + l];

    const bf16x8* wp = wg + (size_t)m0 * 256 + l;    // 256 = 4 kk * 64 lanes
    const bool tok = (t < SEQ_T);
    float* orow = out + (size_t)t * NCOL + lq * 4;

#pragma unroll 2
    for (int m = 0; m < mcnt; ++m) {
        f32x4 acc = (f32x4){0.f, 0.f, 0.f, 0.f};
        bf16x8 ah0 = wp[0];
        bf16x8 ah1 = wp[64];
        bf16x8 ah2 = wp[128];
        bf16x8 ah3 = wp[192];
        acc = __builtin_amdgcn_mfma_f32_16x16x32_bf16(ah0, bs[0], acc, 0, 0, 0);
        acc = __builtin_amdgcn_mfma_f32_16x16x32_bf16(ah1, bs[1], acc, 0, 0, 0);
        acc = __builtin_amdgcn_mfma_f32_16x16x32_bf16(ah2, bs[2], acc, 0, 0, 0);
        acc = __builtin_amdgcn_mfma_f32_16x16x32_bf16(ah3, bs[3], acc, 0, 0, 0);
        wp += 256;
        if (tok)
            *(f32x4*)(orow + (size_t)(m0 + m) * 16) = acc;
    }
}

extern "C" void kernel_launch(void* const* d_in, const int* in_sizes, int n_in,
                              void* d_out, int out_size, void* d_ws, size_t ws_size,
                              hipStream_t stream) {
    const float* weights = (const float*)d_in[0];
    const float* tau     = (const float*)d_in[1];
    const float* spikes  = (const float*)d_in[2];
    const int*   rows    = (const int*)d_in[3];
    const int*   cols    = (const int*)d_in[4];
    float* out = (float*)d_out;

    char* ws = (char*)d_ws;
    unsigned* count = (unsigned*)(ws + WS_COUNT_OFF);
    bf16x8*   spbf  = (bf16x8*)(ws + WS_SPB_OFF);
    uint4*    rec   = (uint4*)(ws + WS_REC_OFF);
    bf16x8*   wg    = (bf16x8*)(ws + WS_WG_OFF);

    hipMemsetAsync(count, 0, NPART * NBINS * sizeof(unsigned), stream);

    int eblocks = (N_EDGES + 255) / 256;
    bucket_kernel<<<eblocks, 256, 0, stream>>>(weights, tau, rows, cols, spikes,
                                               count, rec, spbf);

    scatter_kernel<<<NBINS, 256, 0, stream>>>(count, rec, wg);

    gemm_kernel<<<dim3(249, 4), 256, 0, stream>>>(wg, spbf, out);
}

// Round 13
// 104.535 us; speedup vs baseline: 1.4004x; 1.4004x over previous
//
#include <hip/hip_runtime.h>

// BackgroundNoiseLayer, round 13: consolidation on the round-11 champion.
//   out[t, n*5+r] = sum_k spikes[t,k] * W[k, n*5+r],
//   W[k, c] = scatter-add over edges e (cols[e]=k, rows[e]=n) of weights[e]*tau[e,r]
//
// memset: zero counters [part][bin]
// K1 : bucket edges, 2 edges/thread (two independent atomic chains);
//      16 B records {key, 5 bf16 w*tau} into XCD-local partition; also
//      builds fragment-ordered bf16 spike table spbf[nt][kk][lane].
// K2 : per block (16 neurons = 80 cols): preload records -> zero f32 LDS
//      slice [128][80] (pad rows zeroed -> unguarded convert reads) ->
//      LDS atomic scatter -> convert to bf16 transposed XOR-swizzled LDS
//      (union) -> preload spike frags -> MFMA GEMM with PAIRED-m stores
//      (both 64B halves of each 128B out line issued back-to-back).

#define N_NEURONS 50000
#define N_BKG     100
#define N_SYN     5
#define N_EDGES   500000
#define SEQ_T     250
#define NCOL      (N_NEURONS * N_SYN)   // 250000
#define RPB       16                    // neurons per bin
#define NBINS     (N_NEURONS / RPB)     // 3125
#define NPART     8                     // record partitions (one per XCD)
#define CAP_P     64                    // records per (bin, part): mean 20, +9.8 sigma
#define RECS_BIN  (NPART * CAP_P)       // 512 records / bin
#define CPADF     80                    // f32 slice leading dim
#define BCOLS     80                    // output cols per bin
#define STRIDE_J  37                    // coprime to 390 and 391

#define LDS_BYTES 40960                 // f32 slice 128*80*4 (union w/ bf16 20480)

// d_ws layout
#define WS_COUNT_OFF 0                  // NPART*NBINS u32 = 100 KB
#define WS_SPB_OFF   131072             // 4096 * 16 B = 64 KB spike frags
#define WS_REC_OFF   262144             // NBINS*512*16 B = 25.6 MB

typedef __attribute__((ext_vector_type(8))) short bf16x8;
typedef __attribute__((ext_vector_type(4))) float f32x4;

__device__ inline unsigned short bf16_rne(float f) {
    unsigned u = __builtin_bit_cast(unsigned, f);
    u += 0x7FFFu + ((u >> 16) & 1u);
    return (unsigned short)(u >> 16);
}
__device__ inline float bf16_up(unsigned hw) {
    return __builtin_bit_cast(float, hw << 16);
}

// K1: 2 edges per thread; gids < 4096 also build the fragment-ordered spike
// table: unit gid = (nt*4 + kk)*64 + lane, value[i] = bf16(spikes[t, k0+i]),
// t = nt*16+(lane&15), k0 = kk*32+(lane>>4)*8 (zero-padded).
__global__ __launch_bounds__(256) void bucket_kernel(
        const float* __restrict__ weights,
        const float* __restrict__ tau,
        const int*   __restrict__ rows,
        const int*   __restrict__ cols,
        const float* __restrict__ spikes,
        unsigned* __restrict__ count,
        uint4* __restrict__ rec,
        bf16x8* __restrict__ spbf) {
    int gid = blockIdx.x * 256 + threadIdx.x;
    if (gid < 4096) {
        int lane = gid & 63;
        int kk   = (gid >> 6) & 3;
        int nt   = gid >> 8;
        int t    = nt * 16 + (lane & 15);
        int k0   = kk * 32 + (lane >> 4) * 8;
        bf16x8 v;
#pragma unroll
        for (int i = 0; i < 8; ++i) {
            float s = 0.f;
            if (t < SEQ_T && (k0 + i) < N_BKG)
                s = spikes[t * N_BKG + k0 + i];      // 0/1 -> bf16 exact
            v[i] = (short)bf16_rne(s);
        }
        spbf[gid] = v;
    }
    int part = blockIdx.x & (NPART - 1);         // XCD-local partition
#pragma unroll
    for (int u = 0; u < 2; ++u) {
        int e = gid * 2 + u;                     // two independent chains
        if (e >= N_EDGES) continue;
        int row = rows[e];
        int col = cols[e];
        float w = weights[e];
        const float* tp = tau + (size_t)e * N_SYN;
        int bin = row >> 4;
        unsigned slot = atomicAdd(&count[part * NBINS + bin], 1u);
        if (slot >= CAP_P) continue;             // statistically impossible
        uint4 r;
        r.x = ((unsigned)col << 4) | (unsigned)(row & 15);
        r.y = (unsigned)bf16_rne(w * tp[0]) | ((unsigned)bf16_rne(w * tp[1]) << 16);
        r.z = (unsigned)bf16_rne(w * tp[2]) | ((unsigned)bf16_rne(w * tp[3]) << 16);
        r.w = (unsigned)bf16_rne(w * tp[4]);
        rec[(size_t)bin * RECS_BIN + part * CAP_P + slot] = r;
    }
}

// K2: fused scatter + convert + MFMA GEMM. 3125 blocks x 256 (4 waves).
// Swapped operands: A = W bf16 frag (M = c), B = spike frag (N = t),
// k = (l>>4)*8+i. D: col = t = l&15, row = c = (l>>4)*4+reg -> f32x4
// stores along c (mapping verified rounds 5-12).
__global__ __launch_bounds__(256, 4) void fused_kernel(
        const unsigned* __restrict__ count,
        const uint4* __restrict__ rec,
        const bf16x8* __restrict__ spbf,
        float* __restrict__ out) {
    __shared__ __align__(16) char lds[LDS_BYTES];
    float* slice = (float*)lds;                  // f32 [128][80], rows >=100 stay 0

    const int tid = threadIdx.x;
    const int l   = tid & 63;
    const int wv  = tid >> 6;
    const int lc  = l & 15;
    const int lq  = l >> 4;

    // XCD chunking + strided traversal within the chunk (bijective overall)
    const int orig = blockIdx.x;
    const int xcd  = orig & 7;
    const int j    = orig >> 3;
    const int qx   = (xcd < 5) ? 391 : 390;      // 3125 = 5*391 + 3*390
    const int base = (xcd < 5) ? xcd * 391 : 5 * 391 + (xcd - 5) * 390;
    const int bin  = base + (j * STRIDE_J) % qx;

    // ---- preload records: wave wv owns partitions wv and wv+4 ----
    const uint4* rbin = rec + (size_t)bin * RECS_BIN;
    unsigned cntA = count[wv * NBINS + bin];
    unsigned cntB = count[(4 + wv) * NBINS + bin];
    if (cntA > CAP_P) cntA = CAP_P;
    if (cntB > CAP_P) cntB = CAP_P;
    uint4 ra = rbin[wv * CAP_P + l];             // unguarded: region allocated
    uint4 rb = rbin[(4 + wv) * CAP_P + l];
    bool havea = (unsigned)l < cntA;
    bool haveb = (unsigned)l < cntB;

    // ---- zero f32 slice: 128*80 f32 = 2560 f32x4 (incl. pad rows) ----
    {
        f32x4* s4 = (f32x4*)lds;
        f32x4 z = (f32x4){0.f, 0.f, 0.f, 0.f};
#pragma unroll
        for (int jj = 0; jj < 10; ++jj)
            s4[tid + jj * 256] = z;
    }
    __syncthreads();

    // ---- LDS f32 atomic scatter ----
    if (havea) {
        float* bp = &slice[(ra.x >> 4) * CPADF + (ra.x & 15u) * N_SYN];
        atomicAdd(bp + 0, bf16_up(ra.y & 0xFFFFu));
        atomicAdd(bp + 1, bf16_up(ra.y >> 16));
        atomicAdd(bp + 2, bf16_up(ra.z & 0xFFFFu));
        atomicAdd(bp + 3, bf16_up(ra.z >> 16));
        atomicAdd(bp + 4, bf16_up(ra.w & 0xFFFFu));
    }
    if (haveb) {
        float* bp = &slice[(rb.x >> 4) * CPADF + (rb.x & 15u) * N_SYN];
        atomicAdd(bp + 0, bf16_up(rb.y & 0xFFFFu));
        atomicAdd(bp + 1, bf16_up(rb.y >> 16));
        atomicAdd(bp + 2, bf16_up(rb.z & 0xFFFFu));
        atomicAdd(bp + 3, bf16_up(rb.z >> 16));
        atomicAdd(bp + 4, bf16_up(rb.w & 0xFFFFu));
    }
    __syncthreads();

    // ---- convert once to bf16, transposed [c][k], XOR-swizzled ----
    // 1280 units of (c, 8 consecutive k); unguarded reads (pad rows are 0);
    // reg-staged across the barrier.
    bf16x8 hi[5];
#pragma unroll
    for (int jj = 0; jj < 5; ++jj) {
        int m  = tid + jj * 256;                 // 0..1279
        int c  = m % BCOLS;
        int kb = m / BCOLS;                      // 0..15
#pragma unroll
        for (int i = 0; i < 8; ++i)
            hi[jj][i] = (short)bf16_rne(slice[(kb * 8 + i) * CPADF + c]);
    }
    __syncthreads();
#pragma unroll
    for (int jj = 0; jj < 5; ++jj) {
        int m  = tid + jj * 256;
        int c  = m % BCOLS;
        int kb = m / BCOLS;
        unsigned bo = (unsigned)(((c << 8) + (kb << 4)) ^ ((c & 7) << 4));
        *(bf16x8*)(lds + bo) = hi[jj];
    }

    // ---- preload spike fragments AFTER convert regs die (no spill) ----
    bf16x8 bs[4][4];
#pragma unroll
    for (int n = 0; n < 4; ++n)
#pragma unroll
        for (int kk = 0; kk < 4; ++kk)
            bs[n][kk] = spbf[((wv * 4 + n) * 4 + kk) * 64 + l];
    __syncthreads();

    // ---- MFMA GEMM, paired-m: both 64B halves of each 128B line issue
    //      back-to-back -> guaranteed L2 line merge ----
    const size_t cb = (size_t)bin * BCOLS;
#pragma unroll
    for (int mp = 0; mp < 3; ++mp) {             // m pairs {0,1},{2,3},{4}
        const int m0 = mp * 2;
        const int nm = (mp < 2) ? 2 : 1;
        f32x4 acc[2][4];
#pragma unroll
        for (int mi = 0; mi < 2; ++mi)
#pragma unroll
            for (int n = 0; n < 4; ++n)
                acc[mi][n] = (f32x4){0.f, 0.f, 0.f, 0.f};

#pragma unroll
        for (int mi = 0; mi < 2; ++mi) {
            if (mi >= nm) break;
            int c = (m0 + mi) * 16 + lc;
#pragma unroll
            for (int kk = 0; kk < 4; ++kk) {
                int bor = (((c << 8) + (kk << 6) + (lq << 4)) ^ ((c & 7) << 4));
                bf16x8 ah = *(const bf16x8*)(lds + bor);
#pragma unroll
                for (int n = 0; n < 4; ++n)
                    acc[mi][n] = __builtin_amdgcn_mfma_f32_16x16x32_bf16(
                                     ah, bs[n][kk], acc[mi][n], 0, 0, 0);
            }
        }
        // store the pair: per (n,row) the two 64B halves are adjacent instrs
#pragma unroll
        for (int n = 0; n < 4; ++n) {
            int t = (wv * 4 + n) * 16 + lc;
            if (t < SEQ_T) {
                float* op = out + (size_t)t * NCOL + cb + m0 * 16 + lq * 4;
                *(f32x4*)op = acc[0][n];
                if (nm > 1)
                    *(f32x4*)(op + 16) = acc[1][n];
            }
        }
    }
}

extern "C" void kernel_launch(void* const* d_in, const int* in_sizes, int n_in,
                              void* d_out, int out_size, void* d_ws, size_t ws_size,
                              hipStream_t stream) {
    const float* weights = (const float*)d_in[0];
    const float* tau     = (const float*)d_in[1];
    const float* spikes  = (const float*)d_in[2];
    const int*   rows    = (const int*)d_in[3];
    const int*   cols    = (const int*)d_in[4];
    float* out = (float*)d_out;

    char* ws = (char*)d_ws;
    unsigned* count = (unsigned*)(ws + WS_COUNT_OFF);
    bf16x8*   spbf  = (bf16x8*)(ws + WS_SPB_OFF);
    uint4*    rec   = (uint4*)(ws + WS_REC_OFF);

    hipMemsetAsync(count, 0, NPART * NBINS * sizeof(unsigned), stream);

    int eblocks = (N_EDGES / 2 + 255) / 256;     // 977 (2 edges/thread)
    bucket_kernel<<<eblocks, 256, 0, stream>>>(weights, tau, rows, cols, spikes,
                                               count, rec, spbf);

    fused_kernel<<<NBINS, 256, 0, stream>>>(count, rec, spbf, out);
}

// Round 14
// 102.244 us; speedup vs baseline: 1.4318x; 1.0224x over previous
//
#include <hip/hip_runtime.h>

// BackgroundNoiseLayer, round 14: round-13 champion + latency-exposure fixes.
//   out[t, n*5+r] = sum_k spikes[t,k] * W[k, n*5+r],
//   W[k, c] = scatter-add over edges e (cols[e]=k, rows[e]=n) of weights[e]*tau[e,r]
//
// memset: zero counters [part][bin]
// K1 : bucket edges, 4 edges/thread (four independent atomic->store chains);
//      16 B records {key, 5 bf16 w*tau} into XCD-local partition; also
//      builds fragment-ordered bf16 spike table spbf[nt][kk][lane].
// K2 : per block (16 neurons = 80 cols): preload records -> zero f32 LDS
//      slice [128][80] -> LDS atomic scatter -> convert reads -> (bs spike
//      preload issued; lgkm-only barrier keeps them in flight) -> swizzled
//      bf16 ds_writes -> full barrier -> MFMA GEMM, paired-m 128B stores.

#define N_NEURONS 50000
#define N_BKG     100
#define N_SYN     5
#define N_EDGES   500000
#define SEQ_T     250
#define NCOL      (N_NEURONS * N_SYN)   // 250000
#define RPB       16                    // neurons per bin
#define NBINS     (N_NEURONS / RPB)     // 3125
#define NPART     8                     // record partitions (one per XCD)
#define CAP_P     64                    // records per (bin, part): mean 20, +9.8 sigma
#define RECS_BIN  (NPART * CAP_P)       // 512 records / bin
#define CPADF     80                    // f32 slice leading dim
#define BCOLS     80                    // output cols per bin
#define STRIDE_J  37                    // coprime to 390 and 391

#define LDS_BYTES 40960                 // f32 slice 128*80*4 (union w/ bf16 20480)

// d_ws layout
#define WS_COUNT_OFF 0                  // NPART*NBINS u32 = 100 KB
#define WS_SPB_OFF   131072             // 4096 * 16 B = 64 KB spike frags
#define WS_REC_OFF   262144             // NBINS*512*16 B = 25.6 MB

typedef __attribute__((ext_vector_type(8))) short bf16x8;
typedef __attribute__((ext_vector_type(4))) float f32x4;

// lgkm-only barrier: orders LDS ops across waves, leaves global loads in
// flight. Used ONCE, at the convert read->write boundary (LDS-only deps;
// the in-flight loads are the bs spike fragments consumed after the NEXT
// full barrier).
#define LBAR() asm volatile("s_waitcnt lgkmcnt(0)\n\ts_barrier" ::: "memory")

__device__ inline unsigned short bf16_rne(float f) {
    unsigned u = __builtin_bit_cast(unsigned, f);
    u += 0x7FFFu + ((u >> 16) & 1u);
    return (unsigned short)(u >> 16);
}
__device__ inline float bf16_up(unsigned hw) {
    return __builtin_bit_cast(float, hw << 16);
}

// K1: 4 edges per thread; gids < 4096 also build the fragment-ordered spike
// table: unit gid = (nt*4 + kk)*64 + lane, value[i] = bf16(spikes[t, k0+i]),
// t = nt*16+(lane&15), k0 = kk*32+(lane>>4)*8 (zero-padded).
__global__ __launch_bounds__(256) void bucket_kernel(
        const float* __restrict__ weights,
        const float* __restrict__ tau,
        const int*   __restrict__ rows,
        const int*   __restrict__ cols,
        const float* __restrict__ spikes,
        unsigned* __restrict__ count,
        uint4* __restrict__ rec,
        bf16x8* __restrict__ spbf) {
    int gid = blockIdx.x * 256 + threadIdx.x;
    if (gid < 4096) {
        int lane = gid & 63;
        int kk   = (gid >> 6) & 3;
        int nt   = gid >> 8;
        int t    = nt * 16 + (lane & 15);
        int k0   = kk * 32 + (lane >> 4) * 8;
        bf16x8 v;
#pragma unroll
        for (int i = 0; i < 8; ++i) {
            float s = 0.f;
            if (t < SEQ_T && (k0 + i) < N_BKG)
                s = spikes[t * N_BKG + k0 + i];      // 0/1 -> bf16 exact
            v[i] = (short)bf16_rne(s);
        }
        spbf[gid] = v;
    }
    int part = blockIdx.x & (NPART - 1);         // XCD-local partition
#pragma unroll
    for (int u = 0; u < 4; ++u) {
        int e = gid * 4 + u;                     // four independent chains
        if (e >= N_EDGES) continue;
        int row = rows[e];
        int col = cols[e];
        float w = weights[e];
        const float* tp = tau + (size_t)e * N_SYN;
        int bin = row >> 4;
        unsigned slot = atomicAdd(&count[part * NBINS + bin], 1u);
        if (slot >= CAP_P) continue;             // statistically impossible
        uint4 r;
        r.x = ((unsigned)col << 4) | (unsigned)(row & 15);
        r.y = (unsigned)bf16_rne(w * tp[0]) | ((unsigned)bf16_rne(w * tp[1]) << 16);
        r.z = (unsigned)bf16_rne(w * tp[2]) | ((unsigned)bf16_rne(w * tp[3]) << 16);
        r.w = (unsigned)bf16_rne(w * tp[4]);
        rec[(size_t)bin * RECS_BIN + part * CAP_P + slot] = r;
    }
}

// K2: fused scatter + convert + MFMA GEMM. 3125 blocks x 256 (4 waves).
// Swapped operands: A = W bf16 frag (M = c), B = spike frag (N = t),
// k = (l>>4)*8+i. D: col = t = l&15, row = c = (l>>4)*4+reg -> f32x4
// stores along c (mapping verified rounds 5-13).
__global__ __launch_bounds__(256, 4) void fused_kernel(
        const unsigned* __restrict__ count,
        const uint4* __restrict__ rec,
        const bf16x8* __restrict__ spbf,
        float* __restrict__ out) {
    __shared__ __align__(16) char lds[LDS_BYTES];
    float* slice = (float*)lds;                  // f32 [128][80], rows >=100 stay 0

    const int tid = threadIdx.x;
    const int l   = tid & 63;
    const int wv  = tid >> 6;
    const int lc  = l & 15;
    const int lq  = l >> 4;

    // XCD chunking + strided traversal within the chunk (bijective overall)
    const int orig = blockIdx.x;
    const int xcd  = orig & 7;
    const int j    = orig >> 3;
    const int qx   = (xcd < 5) ? 391 : 390;      // 3125 = 5*391 + 3*390
    const int base = (xcd < 5) ? xcd * 391 : 5 * 391 + (xcd - 5) * 390;
    const int bin  = base + (j * STRIDE_J) % qx;

    // ---- preload records: wave wv owns partitions wv and wv+4 ----
    const uint4* rbin = rec + (size_t)bin * RECS_BIN;
    unsigned cntA = count[wv * NBINS + bin];
    unsigned cntB = count[(4 + wv) * NBINS + bin];
    if (cntA > CAP_P) cntA = CAP_P;
    if (cntB > CAP_P) cntB = CAP_P;
    uint4 ra = rbin[wv * CAP_P + l];             // unguarded: region allocated
    uint4 rb = rbin[(4 + wv) * CAP_P + l];
    bool havea = (unsigned)l < cntA;
    bool haveb = (unsigned)l < cntB;

    // ---- zero f32 slice: 128*80 f32 = 2560 f32x4 (incl. pad rows) ----
    {
        f32x4* s4 = (f32x4*)lds;
        f32x4 z = (f32x4){0.f, 0.f, 0.f, 0.f};
#pragma unroll
        for (int jj = 0; jj < 10; ++jj)
            s4[tid + jj * 256] = z;
    }
    __syncthreads();

    // ---- LDS f32 atomic scatter ----
    if (havea) {
        float* bp = &slice[(ra.x >> 4) * CPADF + (ra.x & 15u) * N_SYN];
        atomicAdd(bp + 0, bf16_up(ra.y & 0xFFFFu));
        atomicAdd(bp + 1, bf16_up(ra.y >> 16));
        atomicAdd(bp + 2, bf16_up(ra.z & 0xFFFFu));
        atomicAdd(bp + 3, bf16_up(ra.z >> 16));
        atomicAdd(bp + 4, bf16_up(ra.w & 0xFFFFu));
    }
    if (haveb) {
        float* bp = &slice[(rb.x >> 4) * CPADF + (rb.x & 15u) * N_SYN];
        atomicAdd(bp + 0, bf16_up(rb.y & 0xFFFFu));
        atomicAdd(bp + 1, bf16_up(rb.y >> 16));
        atomicAdd(bp + 2, bf16_up(rb.z & 0xFFFFu));
        atomicAdd(bp + 3, bf16_up(rb.z >> 16));
        atomicAdd(bp + 4, bf16_up(rb.w & 0xFFFFu));
    }
    __syncthreads();

    // ---- convert reads: slice -> registers (unguarded; pad rows are 0) ----
    bf16x8 hi[5];
#pragma unroll
    for (int jj = 0; jj < 5; ++jj) {
        int m  = tid + jj * 256;                 // 0..1279
        int c  = m % BCOLS;
        int kb = m / BCOLS;                      // 0..15
#pragma unroll
        for (int i = 0; i < 8; ++i)
            hi[jj][i] = (short)bf16_rne(slice[(kb * 8 + i) * CPADF + c]);
    }

    // ---- issue spike-fragment preload NOW; keep in flight across LBAR ----
    bf16x8 bs[4][4];
#pragma unroll
    for (int n = 0; n < 4; ++n)
#pragma unroll
        for (int kk = 0; kk < 4; ++kk)
            bs[n][kk] = spbf[((wv * 4 + n) * 4 + kk) * 64 + l];

    // lgkm-only barrier: all convert READS done before writes overwrite the
    // union; bs global loads stay in flight (drained by the full barrier).
    LBAR();

    // ---- convert writes: transposed [c][k], XOR-swizzled ----
#pragma unroll
    for (int jj = 0; jj < 5; ++jj) {
        int m  = tid + jj * 256;
        int c  = m % BCOLS;
        int kb = m / BCOLS;
        unsigned bo = (unsigned)(((c << 8) + (kb << 4)) ^ ((c & 7) << 4));
        *(bf16x8*)(lds + bo) = hi[jj];
    }
    __syncthreads();                             // drains lgkm + vmcnt (bs ready)

    // ---- MFMA GEMM, paired-m: both 64B halves of each 128B line issue
    //      back-to-back -> guaranteed L2 line merge ----
    const size_t cb = (size_t)bin * BCOLS;
#pragma unroll
    for (int mp = 0; mp < 3; ++mp) {             // m pairs {0,1},{2,3},{4}
        const int m0 = mp * 2;
        const int nm = (mp < 2) ? 2 : 1;
        f32x4 acc[2][4];
#pragma unroll
        for (int mi = 0; mi < 2; ++mi)
#pragma unroll
            for (int n = 0; n < 4; ++n)
                acc[mi][n] = (f32x4){0.f, 0.f, 0.f, 0.f};

#pragma unroll
        for (int mi = 0; mi < 2; ++mi) {
            if (mi >= nm) break;
            int c = (m0 + mi) * 16 + lc;
#pragma unroll
            for (int kk = 0; kk < 4; ++kk) {
                int bor = (((c << 8) + (kk << 6) + (lq << 4)) ^ ((c & 7) << 4));
                bf16x8 ah = *(const bf16x8*)(lds + bor);
#pragma unroll
                for (int n = 0; n < 4; ++n)
                    acc[mi][n] = __builtin_amdgcn_mfma_f32_16x16x32_bf16(
                                     ah, bs[n][kk], acc[mi][n], 0, 0, 0);
            }
        }
        // store the pair: per (n,row) the two 64B halves are adjacent instrs
#pragma unroll
        for (int n = 0; n < 4; ++n) {
            int t = (wv * 4 + n) * 16 + lc;
            if (t < SEQ_T) {
                float* op = out + (size_t)t * NCOL + cb + m0 * 16 + lq * 4;
                *(f32x4*)op = acc[0][n];
                if (nm > 1)
                    *(f32x4*)(op + 16) = acc[1][n];
            }
        }
    }
}

extern "C" void kernel_launch(void* const* d_in, const int* in_sizes, int n_in,
                              void* d_out, int out_size, void* d_ws, size_t ws_size,
                              hipStream_t stream) {
    const float* weights = (const float*)d_in[0];
    const float* tau     = (const float*)d_in[1];
    const float* spikes  = (const float*)d_in[2];
    const int*   rows    = (const int*)d_in[3];
    const int*   cols    = (const int*)d_in[4];
    float* out = (float*)d_out;

    char* ws = (char*)d_ws;
    unsigned* count = (unsigned*)(ws + WS_COUNT_OFF);
    bf16x8*   spbf  = (bf16x8*)(ws + WS_SPB_OFF);
    uint4*    rec   = (uint4*)(ws + WS_REC_OFF);

    hipMemsetAsync(count, 0, NPART * NBINS * sizeof(unsigned), stream);

    int eblocks = (N_EDGES / 4 + 255) / 256;     // 489 (4 edges/thread)
    bucket_kernel<<<eblocks, 256, 0, stream>>>(weights, tau, rows, cols, spikes,
                                               count, rec, spbf);

    fused_kernel<<<NBINS, 256, 0, stream>>>(count, rec, spbf, out);
}